// Round 2
// baseline (3487.703 us; speedup 1.0000x reference)
//
#include <hip/hip_runtime.h>
#include <math.h>

#define BB 128
#define TT 32
#define DDIM 64
#define SS 32
#define VV 8192
#define MAXREC 8
#define NBLK 256
#define NTHR 256

// workspace byte offsets
#define OFF_ZBUF  0u          // 128*128 f32 = 65536 (z_flat rows, linear)
#define OFF_Z2    65536u      // 128 f32 (+pad)
#define OFF_FIN   66048u      // 3*128 u64 = 3072 (rotating argmin buffers)
#define OFF_FLG   69120u      // 16 u32
#define OFF_BAR   69184u      // 256 u32 (two-level barrier)
#define OFF_OUTH  70656u      // 4096*128 f32 = 2097152
#define OFF_RST   2167808u    // 128*4 f32

#define LOGN 33554432u        // 128*32*8192
#define TWO_PI_F 6.283185307179586f

#define AT_LDR(p)    __hip_atomic_load((p), __ATOMIC_RELAXED, __HIP_MEMORY_SCOPE_AGENT)
#define AT_LDA(p)    __hip_atomic_load((p), __ATOMIC_ACQUIRE, __HIP_MEMORY_SCOPE_AGENT)
#define AT_STR(p, v) __hip_atomic_store((p), (v), __ATOMIC_RELAXED, __HIP_MEMORY_SCOPE_AGENT)

__device__ __forceinline__ float wredsum(float v) {
#pragma unroll
  for (int m = 32; m > 0; m >>= 1) v += __shfl_xor(v, m);
  return v;
}

// monotone float->u32, pack with idx: u64-min == (min dist, then min idx) == jnp.argmin tie-break
__device__ __forceinline__ unsigned long long packkey(float d, unsigned c) {
  unsigned u = __float_as_uint(d);
  u = (u & 0x80000000u) ? ~u : (u | 0x80000000u);
  return ((unsigned long long)u << 32) | c;
}

// two-level grid barrier: 8 groups x 32 blocks
__device__ __forceinline__ void gsync(unsigned* bar) {
  __syncthreads();
  if (threadIdx.x == 0) {
    __threadfence();
    const int g = blockIdx.x >> 5;
    unsigned gen = AT_LDR(&bar[192]);
    unsigned a = __hip_atomic_fetch_add(&bar[g * 16], 1u, __ATOMIC_ACQ_REL, __HIP_MEMORY_SCOPE_AGENT);
    if (a == 31u) {
      AT_STR(&bar[g * 16], 0u);
      unsigned b = __hip_atomic_fetch_add(&bar[160], 1u, __ATOMIC_ACQ_REL, __HIP_MEMORY_SCOPE_AGENT);
      if (b == 7u) {
        AT_STR(&bar[160], 0u);
        __hip_atomic_fetch_add(&bar[192], 1u, __ATOMIC_RELEASE, __HIP_MEMORY_SCOPE_AGENT);
      }
    }
    while (AT_LDA(&bar[192]) == gen) __builtin_amdgcn_s_sleep(1);
    __threadfence();
  }
  __syncthreads();
}

__global__ __launch_bounds__(256) void sacrsn_init(char* __restrict__ ws) {
  unsigned long long* fin = (unsigned long long*)(ws + OFF_FIN);
  unsigned* flg = (unsigned*)(ws + OFF_FLG);
  unsigned* bar = (unsigned*)(ws + OFF_BAR);
  const int tid = threadIdx.x;
  for (int i = tid; i < 384; i += 256) fin[i] = ~0ull;
  if (tid < 16) flg[tid] = 0u;
  bar[tid] = 0u;
}

__global__ __launch_bounds__(NTHR) void sacrsn_main(
    const int* __restrict__ x_seq, const float* __restrict__ enc,
    const float* __restrict__ vqe,
    const float* __restrict__ nrg, const float* __restrict__ nrb,
    const float* __restrict__ nig, const float* __restrict__ nib,
    const float* __restrict__ qWr, const float* __restrict__ qbr,
    const float* __restrict__ qWi, const float* __restrict__ qbi,
    const float* __restrict__ gtw, const float* __restrict__ gtb,
    const float* __restrict__ aW, const float* __restrict__ ab,
    const float* __restrict__ hbp, const float* __restrict__ igp,
    float* __restrict__ dout, char* __restrict__ ws)
{
  float* zbuf  = (float*)(ws + OFF_ZBUF);
  float* z2buf = (float*)(ws + OFF_Z2);
  unsigned long long* fin = (unsigned long long*)(ws + OFF_FIN);
  unsigned* flg = (unsigned*)(ws + OFF_FLG);
  unsigned* bar = (unsigned*)(ws + OFF_BAR);
  float* outh  = (float*)(ws + OFF_OUTH);
  float* rst   = (float*)(ws + OFF_RST);

  const int tid = threadIdx.x;
  const int wv = tid >> 6, ln = tid & 63;
  const int blk = blockIdx.x;
  const bool owner = (blk < 128);

  // ---- LDS ----
  __shared__ float els[32 * 128];      // this block's 32 codes, unit-swizzled
  __shared__ float zloc[128 * 128];    // all rows' z, unit-swizzled
  __shared__ float memLr[32 * 65];
  __shared__ float memLi[32 * 65];
  __shared__ unsigned long long vtmp[128][8];
  __shared__ float gwrowL[128], pangL[64], zfmL[128], zqL[128];
  __shared__ float qkL[6][64], simL[32], attnL[32], mrL[64], miL[64];
  __shared__ unsigned idxL[128];
  __shared__ float arbWL[3 * 128];
  __shared__ float esqL[32];
  __shared__ float scalL[8], arbL[4], entpL[2], vqpL[2], wsumL[2], z2pL[2];
  __shared__ float accL[4], totL[4];
  __shared__ float actL;

  const float alpha = 1.0f / (1.0f + expf(-igp[0]));
  const float onema = 1.0f - alpha;
  const float hbias = log1pf(expf(hbp[0]));
  const float gtb0 = gtb[0];

  float lnG = 0.0f, lnB = 0.0f, gtwv = 0.0f;
  if (tid < 64) { lnG = nrg[tid]; lnB = nrb[tid]; }
  else if (tid < 128) { lnG = nig[tid - 64]; lnB = nib[tid - 64]; }
  if (tid < 128) gtwv = gtw[tid];

  // ---- one-time LDS init ----
  for (int i = tid; i < 32 * 65; i += 256) { memLr[i] = 0.0f; memLi[i] = 0.0f; }
  if (tid < 128) gwrowL[tid] = 0.0f;
  if (tid < 4) { totL[tid] = 0.0f; accL[tid] = 0.0f; }
  for (int i = tid; i < 384; i += 256) arbWL[i] = aW[i];
#pragma unroll
  for (int j = 0; j < 4; ++j) {
    int f4 = tid + j * 256;
    int c = f4 >> 5, k4 = f4 & 31;
    float4 v = *(const float4*)&vqe[((size_t)(blk * 32 + c) << 7) + (k4 << 2)];
    *(float4*)&els[(c << 7) + ((k4 ^ c) << 2)] = v;
  }
  __syncthreads();
  if (tid < 32) {
    float s = 0.0f;
#pragma unroll 8
    for (int k4 = 0; k4 < 32; ++k4) {
      float4 v = *(const float4*)&els[(tid << 7) + ((k4 ^ tid) << 2)];
      s = fmaf(v.x, v.x, fmaf(v.y, v.y, fmaf(v.z, v.z, fmaf(v.w, v.w, s))));
    }
    esqL[tid] = s;
  }
  __syncthreads();

  unsigned pcur = 0;

  for (int t = 0; t < TT; ++t) {
    for (int it = 0; it < MAXREC; ++it) {
      // ================= A: merge (it0) + LN own row -> zbuf =================
      if (blk == 0 && tid == 0) AT_STR(&flg[it + 1], 0u);
      if (owner) {
        float val = 0.0f;
        if (it == 0) {
          float pr = 0.0f, gr = 0.0f;
          if (tid < 128) {
            pr = gwrowL[tid];
            int tok = x_seq[blk * TT + t];
            gr = fmaf(alpha, pr, onema * enc[((size_t)tok << 7) + tid]);
          }
          if (t > 0 && tid < 128) {
            outh[((size_t)blk * TT + (t - 1)) * 128 + tid] = pr;
            float part = wredsum(pr * gtwv);
            if (ln == 0) wsumL[wv] = part;
          }
          if (tid < 4) { if (t > 0) totL[tid] += accL[tid]; accL[tid] = 0.0f; }
          if (tid == 0) actL = 1.0f;
          if (tid >= 64 && tid < 128) zqL[tid - 64] = gr;  // reuse zqL as gi exchange
          __syncthreads();
          if (t > 0 && tid < 128) {
            float wg = 1.0f / (1.0f + expf(-(wsumL[0] + wsumL[1] + gtb0)));
            int slot = 32 - t;
            float* m = (tid < 64) ? &memLr[slot * 65 + tid] : &memLi[slot * 65 + (tid - 64)];
            *m = fmaf(wg, pr, (1.0f - wg) * (*m));
          }
          if (tid < 64) pangL[tid] = atan2f(zqL[tid], gr);
          if (tid < 128) gwrowL[tid] = gr;
          val = gr;
        } else {
          val = (tid < 128) ? gwrowL[tid] : 0.0f;
        }
        if (tid < 128) {
          float mu = wredsum(val) * 0.015625f;
          float xc = val - mu;
          float vr = wredsum(xc * xc) * 0.015625f;
          float z = xc * (1.0f / sqrtf(vr + 1e-5f)) * lnG + lnB;
          zfmL[tid] = z;
          zbuf[(blk << 7) + tid] = z;
          float zz = wredsum(z * z);
          if (ln == 0) z2pL[wv] = zz;
        }
        __syncthreads();
        if (tid == 0) z2buf[blk] = z2pL[0] + z2pL[1];
      }
      gsync(bar);
      // flag: set in C(it-1), ordered by the gsync above
      if (it > 0 && AT_LDR(&flg[it]) == 0u) break;

      // ================= B: VQ 32 codes x 128 rows + atomicMin =================
      const unsigned pnxt = (pcur + 1u == 3u) ? 0u : pcur + 1u;
      {
        if (owner && tid == 0) fin[pnxt * 128 + blk] = ~0ull;
        const int rt = ln & 7, ct = ln >> 3;
        int rowA[4]; float z2r[4];
#pragma unroll
        for (int rr = 0; rr < 4; ++rr) rowA[rr] = (wv << 5) + rt + rr * 8;
#pragma unroll
        for (int rr = 0; rr < 4; ++rr) z2r[rr] = z2buf[rowA[rr]];
        // stage all rows' z into LDS (swizzled)
#pragma unroll 4
        for (int i = 0; i < 16; ++i) {
          int f4 = i * 64 + ln;
          int row = (wv << 5) + (f4 >> 5);
          int k4 = f4 & 31;
          float4 v = *(const float4*)&zbuf[(row << 7) + (k4 << 2)];
          *(float4*)&zloc[(row << 7) + ((k4 ^ (row & 31)) << 2)] = v;
        }
        __syncthreads();
        float acc[4][4];
#pragma unroll
        for (int rr = 0; rr < 4; ++rr)
#pragma unroll
          for (int cc = 0; cc < 4; ++cc) acc[rr][cc] = 0.0f;
#pragma unroll 2
        for (int k4 = 0; k4 < 32; ++k4) {
          float4 zv[4], ev[4];
#pragma unroll
          for (int rr = 0; rr < 4; ++rr) {
            int rs = rt + rr * 8;
            zv[rr] = *(const float4*)&zloc[(rowA[rr] << 7) + ((k4 ^ rs) << 2)];
          }
#pragma unroll
          for (int cc = 0; cc < 4; ++cc) {
            int cl = ct + cc * 8;
            ev[cc] = *(const float4*)&els[(cl << 7) + ((k4 ^ cl) << 2)];
          }
#pragma unroll
          for (int rr = 0; rr < 4; ++rr)
#pragma unroll
            for (int cc = 0; cc < 4; ++cc)
              acc[rr][cc] = fmaf(zv[rr].x, ev[cc].x, fmaf(zv[rr].y, ev[cc].y,
                            fmaf(zv[rr].z, ev[cc].z, fmaf(zv[rr].w, ev[cc].w, acc[rr][cc]))));
        }
#pragma unroll
        for (int rr = 0; rr < 4; ++rr) {
          unsigned long long key = ~0ull;
#pragma unroll
          for (int cc = 0; cc < 4; ++cc) {
            int cl = ct + cc * 8;
            float d2 = (z2r[rr] - 2.0f * acc[rr][cc]) + esqL[cl];
            unsigned long long p = packkey(d2, (unsigned)(blk * 32 + cl));
            if (p < key) key = p;
          }
          vtmp[rowA[rr]][ct] = key;
        }
        __syncthreads();
        if (tid < 128) {
          unsigned long long k = vtmp[tid][0];
#pragma unroll
          for (int w = 1; w < 8; ++w) { unsigned long long o = vtmp[tid][w]; if (o < k) k = o; }
          unsigned long long cur = fin[pcur * 128 + tid];
          if (k < cur) atomicMin(&fin[pcur * 128 + tid], k);
        }
      }
      gsync(bar);

      // ================= C: row update (blocks 0..127) =================
      if (owner) {
        // s0: final idx for all rows
        if (tid < 128) idxL[tid] = (unsigned)fin[pcur * 128 + tid];
        __syncthreads();
        const unsigned ii = idxL[blk];
        const float aold = actL;
        // s1: entropy (waves 0-1), vq_loss + z_q fetch (waves 2-3)
        if (tid < 128) {
          unsigned my = idxL[tid];
          int c = 0;
          for (int j = 0; j < 128; ++j) c += (idxL[j] == my) ? 1 : 0;
          float term = -0.0078125f * logf((float)c * 0.0078125f + 1e-10f);
          term = wredsum(term);
          if (ln == 0) entpL[wv] = term;
        } else {
          int d = tid - 128;
          float zq = vqe[((size_t)ii << 7) + d];
          zqL[d] = zq;
          float df = zq - zfmL[d];
          float s = wredsum(df * df);
          if (ln == 0) vqpL[wv - 2] = s;
        }
        __syncthreads();
        // s2: clin q,k,v (0..191) | sim (192..223) | arb (224..226)
        if (tid < 192) {
          const int h = tid >> 6, j = tid & 63;
          const float* wr = qWr + h * 4096 + j * 64;
          const float* wi = qWi + h * 4096 + j * 64;
          float da = 0.0f, db_ = 0.0f, dc = 0.0f, de = 0.0f;
#pragma unroll 4
          for (int d4 = 0; d4 < 64; d4 += 4) {
            float4 wrv = *(const float4*)&wr[d4];
            float4 wiv = *(const float4*)&wi[d4];
            float4 crv = *(const float4*)&zfmL[d4];
            float4 civ = *(const float4*)&zfmL[64 + d4];
            da = fmaf(crv.x, wrv.x, fmaf(crv.y, wrv.y, fmaf(crv.z, wrv.z, fmaf(crv.w, wrv.w, da))));
            db_ = fmaf(civ.x, wiv.x, fmaf(civ.y, wiv.y, fmaf(civ.z, wiv.z, fmaf(civ.w, wiv.w, db_))));
            dc = fmaf(civ.x, wrv.x, fmaf(civ.y, wrv.y, fmaf(civ.z, wrv.z, fmaf(civ.w, wrv.w, dc))));
            de = fmaf(crv.x, wiv.x, fmaf(crv.y, wiv.y, fmaf(crv.z, wiv.z, fmaf(crv.w, wiv.w, de))));
          }
          float brv = qbr[h * 64 + j], biv = qbi[h * 64 + j];
          qkL[2 * h][j] = da + brv - db_ - biv;
          qkL[2 * h + 1][j] = dc + brv + de + biv;
        } else if (tid < 224) {
          const int s = tid - 192;
          float a2 = 0.0f;
          for (int d = 0; d < 64; ++d)
            a2 = fmaf(memLr[s * 65 + d], zfmL[d], fmaf(memLi[s * 65 + d], zfmL[64 + d], a2));
          simL[s] = a2;
        } else if (tid < 227) {
          const int h = tid - 224;
          float a2 = ab[h];
          for (int k2 = 0; k2 < 128; ++k2) a2 = fmaf(zfmL[k2], arbWL[h * 128 + k2], a2);
          arbL[h] = a2;
        }
        __syncthreads();
        // s3: gate | attn softmax | arb softmax | scalar combines
        if (tid < 64) {
          float p = fmaf(qkL[0][tid], qkL[2][tid], qkL[1][tid] * qkL[3][tid]);
          p = wredsum(p);
          if (tid == 0) scalL[0] = 1.0f / (1.0f + expf(-p));
        } else if (tid < 96) {
          const int s = tid - 64;
          float v = simL[s];
          float m = v;
#pragma unroll
          for (int msk = 16; msk > 0; msk >>= 1) m = fmaxf(m, __shfl_xor(m, msk));
          float e = expf(v - m);
          float ss = e;
#pragma unroll
          for (int msk = 16; msk > 0; msk >>= 1) ss += __shfl_xor(ss, msk);
          attnL[s] = e / ss;
        } else if (tid == 96) {
          float a0 = arbL[0], a1 = arbL[1], a2 = arbL[2];
          float m = fmaxf(a0, fmaxf(a1, a2));
          float e0 = expf(a0 - m), e1 = expf(a1 - m), e2 = expf(a2 - m);
          float s = e0 + e1 + e2;
          scalL[3] = e0 / s; scalL[4] = e1 / s; scalL[5] = e2 / s;
        } else if (tid == 97) {
          scalL[2] = entpL[0] + entpL[1];
          scalL[1] = 1.25f * (vqpL[0] + vqpL[1]) * 0.0078125f;
        }
        __syncthreads();
        // s4: attention readout m_r / m_i
        if (tid < 128) {
          const int d = ln;
          const float* ml = (wv == 0) ? memLr : memLi;
          float a2 = 0.0f;
#pragma unroll 4
          for (int s2 = 0; s2 < 32; ++s2) a2 = fmaf(attnL[s2], ml[s2 * 65 + d], a2);
          if (wv == 0) mrL[d] = a2; else miL[d] = a2;
        }
        __syncthreads();
        // s5: candidate, phase diff, halting, stats
        const bool mf = aold > 0.5f;
        if (tid < 64) {
          const int d = tid;
          float gate = scalL[0], g0 = scalL[3], g1 = scalL[4], g2 = scalL[5];
          float cr = zfmL[d], ci = zfmL[64 + d];
          float ur = fmaf(g0, qkL[4][d] * gate, fmaf(g1, mrL[d], g2 * zqL[d]));
          float ui = fmaf(g0, qkL[5][d] * gate, fmaf(g1, miL[d], g2 * zqL[64 + d]));
          float cdr = fmaf(0.4f, ur, 0.6f * cr);
          float cdi = fmaf(0.4f, ui, 0.6f * ci);
          float ang = atan2f(cdi, cdr);
          float df = fabsf(ang - pangL[d]);
          df = fminf(df, TWO_PI_F - df);
          pangL[d] = ang;
          float dmean = wredsum(df) * 0.015625f;
          if (mf) { gwrowL[d] = cdr; gwrowL[64 + d] = cdi; }
          if (d == 0) {
            float vql = scalL[1];
            accL[3] += aold * dmean;
            accL[2] += aold * 0.01f;
            if (mf) {
              accL[0] = vql;
              accL[1] = scalL[2];
              dout[(size_t)LOGN + 4 + (size_t)blk * TT + t] = (float)ii;
            }
            bool stop = (hbias - vql) > 0.0f;
            float anew = stop ? 0.0f : aold;
            actL = anew;
            if (anew > 0.5f)
              __hip_atomic_fetch_or(&flg[it + 1], 1u, __ATOMIC_RELAXED, __HIP_MEMORY_SCOPE_AGENT);
          }
        }
        __syncthreads();
      }
      pcur = pnxt;
    } // it
  } // t

  // epilogue: final gw out + stats flush
  if (owner) {
    if (tid < 128) outh[((size_t)blk * TT + (TT - 1)) * 128 + tid] = gwrowL[tid];
    if (tid < 4) rst[blk * 4 + tid] = totL[tid] + accL[tid];
  }
}

__global__ __launch_bounds__(256) void sacrsn_dec(
    const float* __restrict__ dW, const float* __restrict__ dbv,
    float* __restrict__ dout, const char* __restrict__ ws)
{
  const float* outh = (const float*)(ws + OFF_OUTH);
  const float* rst = (const float*)(ws + OFF_RST);
  __shared__ float As[4096];
  __shared__ float Bs[4096];
  const int tid = threadIdx.x;
  const int bx = blockIdx.x & 127;
  const int by = blockIdx.x >> 7;
  const int n0 = bx << 6, m0 = by << 6;
  if (blockIdx.x == 0 && tid < 4) {
    float s = 0.0f;
    for (int r = 0; r < 128; ++r) s += rst[r * 4 + tid];
    dout[(size_t)LOGN + tid] = s * (1.0f / 4096.0f);
  }
  const int ty = tid >> 4, tx = tid & 15;
  float acc[4][4];
#pragma unroll
  for (int i = 0; i < 4; ++i)
#pragma unroll
    for (int j = 0; j < 4; ++j) acc[i][j] = 0.0f;
  for (int kh = 0; kh < 2; ++kh) {
    for (int u = tid; u < 1024; u += 256) {
      const int row = u >> 4, un = u & 15;
      const int sw = ((un ^ row) & 15) << 2;
      *(float4*)&As[(row << 6) + sw] =
          *(const float4*)&outh[((size_t)(m0 + row) << 7) + (kh << 6) + (un << 2)];
      *(float4*)&Bs[(row << 6) + sw] =
          *(const float4*)&dW[((size_t)(n0 + row) << 7) + (kh << 6) + (un << 2)];
    }
    __syncthreads();
#pragma unroll 4
    for (int k4 = 0; k4 < 16; ++k4) {
      float4 a[4], b[4];
#pragma unroll
      for (int ii = 0; ii < 4; ++ii) {
        const int row = (ty << 2) + ii;
        a[ii] = *(const float4*)&As[(row << 6) + (((k4 ^ row) & 15) << 2)];
      }
#pragma unroll
      for (int jj = 0; jj < 4; ++jj) {
        const int row = (tx << 2) + jj;
        b[jj] = *(const float4*)&Bs[(row << 6) + (((k4 ^ row) & 15) << 2)];
      }
#pragma unroll
      for (int ii = 0; ii < 4; ++ii)
#pragma unroll
        for (int jj = 0; jj < 4; ++jj)
          acc[ii][jj] = fmaf(a[ii].x, b[jj].x, fmaf(a[ii].y, b[jj].y,
                        fmaf(a[ii].z, b[jj].z, fmaf(a[ii].w, b[jj].w, acc[ii][jj]))));
    }
    __syncthreads();
  }
#pragma unroll
  for (int ii = 0; ii < 4; ++ii) {
    const int m = m0 + (ty << 2) + ii;
    const int v0 = n0 + (tx << 2);
    float4 o;
    o.x = acc[ii][0] + dbv[v0];
    o.y = acc[ii][1] + dbv[v0 + 1];
    o.z = acc[ii][2] + dbv[v0 + 2];
    o.w = acc[ii][3] + dbv[v0 + 3];
    *(float4*)&dout[((size_t)m << 13) + v0] = o;
  }
}

extern "C" void kernel_launch(void* const* d_in, const int* in_sizes, int n_in,
                              void* d_out, int out_size, void* d_ws, size_t ws_size,
                              hipStream_t stream) {
  (void)in_sizes; (void)n_in; (void)out_size; (void)ws_size;
  const int*   x_seq = (const int*)d_in[0];
  const float* enc = (const float*)d_in[1];
  const float* vq  = (const float*)d_in[2];
  const float* nrg = (const float*)d_in[3];
  const float* nrb = (const float*)d_in[4];
  const float* nig = (const float*)d_in[5];
  const float* nib = (const float*)d_in[6];
  const float* qWr = (const float*)d_in[7];
  const float* qbr = (const float*)d_in[8];
  const float* qWi = (const float*)d_in[9];
  const float* qbi = (const float*)d_in[10];
  const float* gtw = (const float*)d_in[11];
  const float* gtb = (const float*)d_in[12];
  const float* aW  = (const float*)d_in[13];
  const float* ab  = (const float*)d_in[14];
  const float* dW  = (const float*)d_in[15];
  const float* db  = (const float*)d_in[16];
  const float* hb  = (const float*)d_in[17];
  const float* ig  = (const float*)d_in[18];
  char* ws = (char*)d_ws;
  float* out = (float*)d_out;
  hipLaunchKernelGGL(sacrsn_init, dim3(1), dim3(256), 0, stream, ws);
  hipLaunchKernelGGL(sacrsn_main, dim3(NBLK), dim3(NTHR), 0, stream,
                     x_seq, enc, vq, nrg, nrb, nig, nib, qWr, qbr, qWi, qbi,
                     gtw, gtb, aW, ab, hb, ig, out, ws);
  hipLaunchKernelGGL(sacrsn_dec, dim3(8192), dim3(256), 0, stream, dW, db, out, ws);
}

// Round 3
// 973.714 us; speedup vs baseline: 3.5819x; 3.5819x over previous
//
#include <hip/hip_runtime.h>
#include <math.h>

#define BB 128
#define TT 32
#define SS 32
#define VV 8192
#define MAXREC 8
#define NBLK 256
#define NTHR 256

// workspace byte offsets
#define OFF_ZBUF  0u          // 128*128 f32 = 65536 (z rows, linear)
#define OFF_Z2    65536u      // 128 f32
#define OFF_FIN   66048u      // 2*128 u64 = 2048 (double-buffered argmin)
#define OFF_BAR   68096u      // 256 u32 (two-level barrier)
#define OFF_OUTH  69120u      // 4096*128 f32 = 2097152
#define OFF_RST   2166272u    // 128*4 f32

#define LOGN 33554432u        // 128*32*8192
#define TWO_PI_F 6.283185307179586f

typedef float f32x4 __attribute__((ext_vector_type(4)));

__device__ __forceinline__ float wredsum(float v) {
#pragma unroll
  for (int m = 32; m > 0; m >>= 1) v += __shfl_xor(v, m);
  return v;
}

// monotone float->u32, pack with idx: u64-min == (min dist, then min idx) == jnp.argmin tie-break
__device__ __forceinline__ unsigned long long packkey(float d, unsigned c) {
  unsigned u = __float_as_uint(d);
  u = (u & 0x80000000u) ? ~u : (u | 0x80000000u);
  return ((unsigned long long)u << 32) | c;
}
__device__ __forceinline__ float unpackd2(unsigned long long key) {
  unsigned hi = (unsigned)(key >> 32);
  unsigned orig = (hi & 0x80000000u) ? (hi & 0x7fffffffu) : ~hi;
  return __uint_as_float(orig);
}

// ---- coherent (cross-XCD, L2-bypass) accesses: no cache-maintenance walks ----
__device__ __forceinline__ unsigned ld_coh32(const unsigned* p) {
  unsigned v;
  asm volatile("global_load_dword %0, %1, off sc0 sc1\n\ts_waitcnt vmcnt(0)"
               : "=&v"(v) : "v"(p) : "memory");
  return v;
}
__device__ __forceinline__ float ld_coh_f32(const float* p) {
  float v;
  asm volatile("global_load_dword %0, %1, off sc0 sc1\n\ts_waitcnt vmcnt(0)"
               : "=&v"(v) : "v"(p) : "memory");
  return v;
}
__device__ __forceinline__ unsigned long long ld_coh64(const unsigned long long* p) {
  unsigned long long v;
  asm volatile("global_load_dwordx2 %0, %1, off sc0 sc1\n\ts_waitcnt vmcnt(0)"
               : "=&v"(v) : "v"(p) : "memory");
  return v;
}
__device__ __forceinline__ void st_coh_f32(float* p, float v) {
  asm volatile("global_store_dword %0, %1, off sc0 sc1" :: "v"(p), "v"(v) : "memory");
}
__device__ __forceinline__ void st_coh64(unsigned long long* p, unsigned long long v) {
  asm volatile("global_store_dwordx2 %0, %1, off sc0 sc1" :: "v"(p), "v"(v) : "memory");
}
__device__ __forceinline__ void st_coh32_wait(unsigned* p, unsigned v) {
  asm volatile("global_store_dword %0, %1, off sc0 sc1\n\ts_waitcnt vmcnt(0)"
               :: "v"(p), "v"(v) : "memory");
}
__device__ __forceinline__ void ld_coh_f4x4(const f32x4* p0, const f32x4* p1,
                                            const f32x4* p2, const f32x4* p3,
                                            f32x4& a, f32x4& b, f32x4& c, f32x4& d) {
  asm volatile(
      "global_load_dwordx4 %0, %4, off sc0 sc1\n\t"
      "global_load_dwordx4 %1, %5, off sc0 sc1\n\t"
      "global_load_dwordx4 %2, %6, off sc0 sc1\n\t"
      "global_load_dwordx4 %3, %7, off sc0 sc1\n\t"
      "s_waitcnt vmcnt(0)"
      : "=&v"(a), "=&v"(b), "=&v"(c), "=&v"(d)
      : "v"(p0), "v"(p1), "v"(p2), "v"(p3)
      : "memory");
}

// fence-free two-level grid barrier: relaxed RMWs + coherent polls.
// __syncthreads() drains each wave's vmcnt, so prior sc1 stores / atomics are
// globally visible (at the coherent point) before the arrival RMW issues.
__device__ __forceinline__ void gsync(unsigned* bar) {
  __syncthreads();
  if (threadIdx.x == 0) {
    const int g = blockIdx.x >> 5;
    unsigned gen = ld_coh32(&bar[192]);  // snapshot strictly before arrival
    unsigned a = __hip_atomic_fetch_add(&bar[g * 16], 1u, __ATOMIC_RELAXED, __HIP_MEMORY_SCOPE_AGENT);
    if (a == 31u) {
      st_coh32_wait(&bar[g * 16], 0u);
      unsigned b = __hip_atomic_fetch_add(&bar[160], 1u, __ATOMIC_RELAXED, __HIP_MEMORY_SCOPE_AGENT);
      if (b == 7u) {
        st_coh32_wait(&bar[160], 0u);
        __hip_atomic_fetch_add(&bar[192], 1u, __ATOMIC_RELAXED, __HIP_MEMORY_SCOPE_AGENT);
      }
    }
    while (ld_coh32(&bar[192]) == gen) __builtin_amdgcn_s_sleep(1);
  }
  __syncthreads();
}

__global__ __launch_bounds__(256) void sacrsn_init(char* __restrict__ ws) {
  unsigned long long* fin = (unsigned long long*)(ws + OFF_FIN);
  unsigned* bar = (unsigned*)(ws + OFF_BAR);
  const int tid = threadIdx.x;
  fin[tid] = ~0ull;      // both buffers: 2*128 = 256
  bar[tid] = 0u;
}

__global__ __launch_bounds__(NTHR) void sacrsn_main(
    const int* __restrict__ x_seq, const float* __restrict__ enc,
    const float* __restrict__ vqe,
    const float* __restrict__ nrg, const float* __restrict__ nrb,
    const float* __restrict__ nig, const float* __restrict__ nib,
    const float* __restrict__ qWr, const float* __restrict__ qbr,
    const float* __restrict__ qWi, const float* __restrict__ qbi,
    const float* __restrict__ gtw, const float* __restrict__ gtb,
    const float* __restrict__ aW, const float* __restrict__ ab,
    const float* __restrict__ hbp, const float* __restrict__ igp,
    float* __restrict__ dout, char* __restrict__ ws)
{
  float* zbuf  = (float*)(ws + OFF_ZBUF);
  float* z2buf = (float*)(ws + OFF_Z2);
  unsigned long long* fin = (unsigned long long*)(ws + OFF_FIN);
  unsigned* bar = (unsigned*)(ws + OFF_BAR);
  float* outh  = (float*)(ws + OFF_OUTH);
  float* rst   = (float*)(ws + OFF_RST);

  const int tid = threadIdx.x;
  const int wv = tid >> 6, ln = tid & 63;
  const int blk = blockIdx.x;
  const bool owner = (blk < 128);

  // ---- LDS ----
  __shared__ float els[32 * 128];      // this block's 32 codes, unit-swizzled
  __shared__ float zloc[128 * 128];    // all rows' z, unit-swizzled
  __shared__ float memLr[32 * 65];
  __shared__ float memLi[32 * 65];
  __shared__ unsigned long long vtmp[128][8];
  __shared__ float gwrowL[128], pangL[64], zfmL[128], zqL[128];
  __shared__ float qkL[6][64], simL[32], attnL[32], mrL[64], miL[64];
  __shared__ unsigned idxL[128];
  __shared__ float arbWL[3 * 128];
  __shared__ float esqL[32];
  __shared__ float z2locL[128];
  __shared__ float scalL[8], arbL[4], entpL[2], vqpL[2], wsumL[2], z2pL[2];
  __shared__ float accL[4], totL[4];
  __shared__ unsigned long long actM[2], actN[2];

  const float alpha = 1.0f / (1.0f + expf(-igp[0]));
  const float onema = 1.0f - alpha;
  const float hbias = log1pf(expf(hbp[0]));
  const float gtb0 = gtb[0];

  float lnG = 0.0f, lnB = 0.0f, gtwv = 0.0f;
  if (tid < 64) { lnG = nrg[tid]; lnB = nrb[tid]; }
  else if (tid < 128) { lnG = nig[tid - 64]; lnB = nib[tid - 64]; }
  if (tid < 128) gtwv = gtw[tid];

  // ---- one-time LDS init ----
  for (int i = tid; i < 32 * 65; i += 256) { memLr[i] = 0.0f; memLi[i] = 0.0f; }
  if (tid < 128) gwrowL[tid] = 0.0f;
  if (tid < 4) { totL[tid] = 0.0f; accL[tid] = 0.0f; }
  for (int i = tid; i < 384; i += 256) arbWL[i] = aW[i];
#pragma unroll
  for (int j = 0; j < 4; ++j) {
    int f4 = tid + j * 256;
    int c = f4 >> 5, k4 = f4 & 31;
    float4 v = *(const float4*)&vqe[((size_t)(blk * 32 + c) << 7) + (k4 << 2)];
    *(float4*)&els[(c << 7) + ((k4 ^ c) << 2)] = v;
  }
  __syncthreads();
  if (tid < 32) {
    float s = 0.0f;
#pragma unroll 8
    for (int k4 = 0; k4 < 32; ++k4) {
      float4 v = *(const float4*)&els[(tid << 7) + ((k4 ^ tid) << 2)];
      s = fmaf(v.x, v.x, fmaf(v.y, v.y, fmaf(v.z, v.z, fmaf(v.w, v.w, s))));
    }
    esqL[tid] = s;
  }
  __syncthreads();

  unsigned pcur = 0;

  for (int t = 0; t < TT; ++t) {
    for (int it = 0; it < MAXREC; ++it) {
      // ================= A: merge (it0) + LN own row -> zbuf (coherent) =================
      if (it == 0 && tid < 2) actM[tid] = ~0ull;
      if (owner) {
        float val = 0.0f;
        if (it == 0) {
          float pr = 0.0f, gr = 0.0f;
          if (tid < 128) {
            pr = gwrowL[tid];
            int tok = x_seq[blk * TT + t];
            gr = fmaf(alpha, pr, onema * enc[((size_t)tok << 7) + tid]);
          }
          if (t > 0 && tid < 128) {
            outh[((size_t)blk * TT + (t - 1)) * 128 + tid] = pr;
            float part = wredsum(pr * gtwv);
            if (ln == 0) wsumL[wv] = part;
          }
          if (tid < 4) { if (t > 0) totL[tid] += accL[tid]; accL[tid] = 0.0f; }
          if (tid >= 64 && tid < 128) zqL[tid - 64] = gr;  // gi exchange
          __syncthreads();
          if (t > 0 && tid < 128) {
            float wg = 1.0f / (1.0f + expf(-(wsumL[0] + wsumL[1] + gtb0)));
            int slot = 32 - t;
            float* m = (tid < 64) ? &memLr[slot * 65 + tid] : &memLi[slot * 65 + (tid - 64)];
            *m = fmaf(wg, pr, (1.0f - wg) * (*m));
          }
          if (tid < 64) pangL[tid] = atan2f(zqL[tid], gr);
          if (tid < 128) gwrowL[tid] = gr;
          val = gr;
        } else {
          val = (tid < 128) ? gwrowL[tid] : 0.0f;
        }
        if (tid < 128) {
          float mu = wredsum(val) * 0.015625f;
          float xc = val - mu;
          float vr = wredsum(xc * xc) * 0.015625f;
          float z = xc * (1.0f / sqrtf(vr + 1e-5f)) * lnG + lnB;
          zfmL[tid] = z;
          st_coh_f32(&zbuf[(blk << 7) + tid], z);
          float zz = wredsum(z * z);
          if (ln == 0) z2pL[wv] = zz;
        }
        __syncthreads();
        if (tid == 0) st_coh_f32(&z2buf[blk], z2pL[0] + z2pL[1]);
      }
      gsync(bar);  // g1: z visible to all

      // ================= B: VQ 32 codes x 128 rows + atomicMin =================
      const unsigned pnxt = pcur ^ 1u;
      {
        if (owner && tid == 0) st_coh64(&fin[pnxt * 128 + blk], ~0ull);
        if (tid < 128) z2locL[tid] = ld_coh_f32(&z2buf[tid]);
        // stage all rows' z into LDS (coherent loads, swizzled store)
#pragma unroll
        for (int g4 = 0; g4 < 4; ++g4) {
          const f32x4* p[4]; f32x4 v[4];
#pragma unroll
          for (int u = 0; u < 4; ++u) {
            int f4 = (g4 * 4 + u) * 256 + tid;
            p[u] = (const f32x4*)zbuf + f4;
          }
          ld_coh_f4x4(p[0], p[1], p[2], p[3], v[0], v[1], v[2], v[3]);
#pragma unroll
          for (int u = 0; u < 4; ++u) {
            int f4 = (g4 * 4 + u) * 256 + tid;
            int row = f4 >> 5, k4 = f4 & 31;
            *(f32x4*)&zloc[(row << 7) + ((k4 ^ (row & 31)) << 2)] = v[u];
          }
        }
        __syncthreads();
        const int rt = ln & 7, ct = ln >> 3;
        int rowA[4]; float z2r[4];
#pragma unroll
        for (int rr = 0; rr < 4; ++rr) rowA[rr] = (wv << 5) + rt + rr * 8;
#pragma unroll
        for (int rr = 0; rr < 4; ++rr) z2r[rr] = z2locL[rowA[rr]];
        float acc[4][4];
#pragma unroll
        for (int rr = 0; rr < 4; ++rr)
#pragma unroll
          for (int cc = 0; cc < 4; ++cc) acc[rr][cc] = 0.0f;
#pragma unroll 2
        for (int k4 = 0; k4 < 32; ++k4) {
          float4 zv[4], ev[4];
#pragma unroll
          for (int rr = 0; rr < 4; ++rr) {
            int rs = rt + rr * 8;
            zv[rr] = *(const float4*)&zloc[(rowA[rr] << 7) + ((k4 ^ rs) << 2)];
          }
#pragma unroll
          for (int cc = 0; cc < 4; ++cc) {
            int cl = ct + cc * 8;
            ev[cc] = *(const float4*)&els[(cl << 7) + ((k4 ^ cl) << 2)];
          }
#pragma unroll
          for (int rr = 0; rr < 4; ++rr)
#pragma unroll
            for (int cc = 0; cc < 4; ++cc)
              acc[rr][cc] = fmaf(zv[rr].x, ev[cc].x, fmaf(zv[rr].y, ev[cc].y,
                            fmaf(zv[rr].z, ev[cc].z, fmaf(zv[rr].w, ev[cc].w, acc[rr][cc]))));
        }
#pragma unroll
        for (int rr = 0; rr < 4; ++rr) {
          unsigned long long key = ~0ull;
#pragma unroll
          for (int cc = 0; cc < 4; ++cc) {
            int cl = ct + cc * 8;
            float d2 = (z2r[rr] - 2.0f * acc[rr][cc]) + esqL[cl];
            unsigned long long pk = packkey(d2, (unsigned)(blk * 32 + cl));
            if (pk < key) key = pk;
          }
          vtmp[rowA[rr]][ct] = key;
        }
        __syncthreads();
        if (tid < 128) {
          unsigned long long k = vtmp[tid][0];
#pragma unroll
          for (int w = 1; w < 8; ++w) { unsigned long long o = vtmp[tid][w]; if (o < k) k = o; }
          unsigned long long cur = ld_coh64(&fin[pcur * 128 + tid]);
          if (k < cur) atomicMin(&fin[pcur * 128 + tid], k);
        }
      }
      gsync(bar);  // g2: fin final everywhere

      // ====== consensus: every block derives idx + halt mask from fin keys ======
      const bool aoldb = ((actM[blk >> 6] >> (blk & 63)) & 1ull) != 0ull;
      if (tid < 128) {
        unsigned long long key = ld_coh64(&fin[pcur * 128 + tid]);
        idxL[tid] = (unsigned)key;
        float d2 = unpackd2(key);
        bool act_b = ((actM[tid >> 6] >> (tid & 63)) & 1ull) != 0ull;
        bool stop = (1.25f * 0.0078125f * d2) < hbias;   // pure fn of key -> identical everywhere
        unsigned long long ball = __ballot(act_b && !stop);
        if ((tid & 63) == 0) actN[tid >> 6] = ball;
      }
      __syncthreads();
      const bool anyAct = (actN[0] | actN[1]) != 0ull;
      if (tid < 2) actM[tid] = actN[tid];

      // ================= C: row update (blocks 0..127) =================
      if (owner) {
        const unsigned ii = idxL[blk];
        const bool mf = aoldb;
        const float aold = mf ? 1.0f : 0.0f;
        // s1: entropy (waves 0-1), vq_loss + z_q fetch (waves 2-3)
        if (tid < 128) {
          unsigned my = idxL[tid];
          int c = 0;
          for (int j = 0; j < 128; ++j) c += (idxL[j] == my) ? 1 : 0;
          float term = -0.0078125f * logf((float)c * 0.0078125f + 1e-10f);
          term = wredsum(term);
          if (ln == 0) entpL[wv] = term;
        } else {
          int d = tid - 128;
          float zq = vqe[((size_t)ii << 7) + d];
          zqL[d] = zq;
          float df = zq - zfmL[d];
          float s = wredsum(df * df);
          if (ln == 0) vqpL[wv - 2] = s;
        }
        __syncthreads();
        // s2: clin q,k,v (0..191) | sim (192..223) | arb (224..226)
        if (tid < 192) {
          const int h = tid >> 6, j = tid & 63;
          const float* wr = qWr + h * 4096 + j * 64;
          const float* wi = qWi + h * 4096 + j * 64;
          float da = 0.0f, db_ = 0.0f, dc = 0.0f, de = 0.0f;
#pragma unroll 4
          for (int d4 = 0; d4 < 64; d4 += 4) {
            float4 wrv = *(const float4*)&wr[d4];
            float4 wiv = *(const float4*)&wi[d4];
            float4 crv = *(const float4*)&zfmL[d4];
            float4 civ = *(const float4*)&zfmL[64 + d4];
            da = fmaf(crv.x, wrv.x, fmaf(crv.y, wrv.y, fmaf(crv.z, wrv.z, fmaf(crv.w, wrv.w, da))));
            db_ = fmaf(civ.x, wiv.x, fmaf(civ.y, wiv.y, fmaf(civ.z, wiv.z, fmaf(civ.w, wiv.w, db_))));
            dc = fmaf(civ.x, wrv.x, fmaf(civ.y, wrv.y, fmaf(civ.z, wrv.z, fmaf(civ.w, wrv.w, dc))));
            de = fmaf(crv.x, wiv.x, fmaf(crv.y, wiv.y, fmaf(crv.z, wiv.z, fmaf(crv.w, wiv.w, de))));
          }
          float brv = qbr[h * 64 + j], biv = qbi[h * 64 + j];
          qkL[2 * h][j] = da + brv - db_ - biv;
          qkL[2 * h + 1][j] = dc + brv + de + biv;
        } else if (tid < 224) {
          const int s = tid - 192;
          float a2 = 0.0f;
          for (int d = 0; d < 64; ++d)
            a2 = fmaf(memLr[s * 65 + d], zfmL[d], fmaf(memLi[s * 65 + d], zfmL[64 + d], a2));
          simL[s] = a2;
        } else if (tid < 227) {
          const int h = tid - 224;
          float a2 = ab[h];
          for (int k2 = 0; k2 < 128; ++k2) a2 = fmaf(zfmL[k2], arbWL[h * 128 + k2], a2);
          arbL[h] = a2;
        }
        __syncthreads();
        // s3: gate | attn softmax | arb softmax | scalar combines
        if (tid < 64) {
          float p = fmaf(qkL[0][tid], qkL[2][tid], qkL[1][tid] * qkL[3][tid]);
          p = wredsum(p);
          if (tid == 0) scalL[0] = 1.0f / (1.0f + expf(-p));
        } else if (tid < 96) {
          const int s = tid - 64;
          float v = simL[s];
          float m = v;
#pragma unroll
          for (int msk = 16; msk > 0; msk >>= 1) m = fmaxf(m, __shfl_xor(m, msk));
          float e = expf(v - m);
          float ss = e;
#pragma unroll
          for (int msk = 16; msk > 0; msk >>= 1) ss += __shfl_xor(ss, msk);
          attnL[s] = e / ss;
        } else if (tid == 96) {
          float a0 = arbL[0], a1 = arbL[1], a2 = arbL[2];
          float m = fmaxf(a0, fmaxf(a1, a2));
          float e0 = expf(a0 - m), e1 = expf(a1 - m), e2 = expf(a2 - m);
          float s = e0 + e1 + e2;
          scalL[3] = e0 / s; scalL[4] = e1 / s; scalL[5] = e2 / s;
        } else if (tid == 97) {
          scalL[2] = entpL[0] + entpL[1];
          scalL[1] = 1.25f * (vqpL[0] + vqpL[1]) * 0.0078125f;
        }
        __syncthreads();
        // s4: attention readout m_r / m_i
        if (tid < 128) {
          const int d = ln;
          const float* ml = (wv == 0) ? memLr : memLi;
          float a2 = 0.0f;
#pragma unroll 4
          for (int s2 = 0; s2 < 32; ++s2) a2 = fmaf(attnL[s2], ml[s2 * 65 + d], a2);
          if (wv == 0) mrL[d] = a2; else miL[d] = a2;
        }
        __syncthreads();
        // s5: candidate, phase diff, stats (halting handled by consensus)
        if (tid < 64) {
          const int d = tid;
          float gate = scalL[0], g0 = scalL[3], g1 = scalL[4], g2 = scalL[5];
          float cr = zfmL[d], ci = zfmL[64 + d];
          float ur = fmaf(g0, qkL[4][d] * gate, fmaf(g1, mrL[d], g2 * zqL[d]));
          float ui = fmaf(g0, qkL[5][d] * gate, fmaf(g1, miL[d], g2 * zqL[64 + d]));
          float cdr = fmaf(0.4f, ur, 0.6f * cr);
          float cdi = fmaf(0.4f, ui, 0.6f * ci);
          float ang = atan2f(cdi, cdr);
          float df = fabsf(ang - pangL[d]);
          df = fminf(df, TWO_PI_F - df);
          pangL[d] = ang;
          float dmean = wredsum(df) * 0.015625f;
          if (mf) { gwrowL[d] = cdr; gwrowL[64 + d] = cdi; }
          if (d == 0) {
            accL[3] += aold * dmean;
            accL[2] += aold * 0.01f;
            if (mf) {
              accL[0] = scalL[1];
              accL[1] = scalL[2];
              dout[(size_t)LOGN + 4 + (size_t)blk * TT + t] = (float)ii;
            }
          }
        }
        __syncthreads();
      }
      pcur = pnxt;
      if (!anyAct) break;   // identical decision in every block
    } // it
  } // t

  // epilogue: final gw out + stats flush
  if (owner) {
    if (tid < 128) outh[((size_t)blk * TT + (TT - 1)) * 128 + tid] = gwrowL[tid];
    if (tid < 4) rst[blk * 4 + tid] = totL[tid] + accL[tid];
  }
}

__global__ __launch_bounds__(256) void sacrsn_dec(
    const float* __restrict__ dW, const float* __restrict__ dbv,
    float* __restrict__ dout, const char* __restrict__ ws)
{
  const float* outh = (const float*)(ws + OFF_OUTH);
  const float* rst = (const float*)(ws + OFF_RST);
  __shared__ float As[4096];
  __shared__ float Bs[4096];
  const int tid = threadIdx.x;
  const int bx = blockIdx.x & 127;
  const int by = blockIdx.x >> 7;
  const int n0 = bx << 6, m0 = by << 6;
  if (blockIdx.x == 0 && tid < 4) {
    float s = 0.0f;
    for (int r = 0; r < 128; ++r) s += rst[r * 4 + tid];
    dout[(size_t)LOGN + tid] = s * (1.0f / 4096.0f);
  }
  const int ty = tid >> 4, tx = tid & 15;
  float acc[4][4];
#pragma unroll
  for (int i = 0; i < 4; ++i)
#pragma unroll
    for (int j = 0; j < 4; ++j) acc[i][j] = 0.0f;
  for (int kh = 0; kh < 2; ++kh) {
    for (int u = tid; u < 1024; u += 256) {
      const int row = u >> 4, un = u & 15;
      const int sw = ((un ^ row) & 15) << 2;
      *(float4*)&As[(row << 6) + sw] =
          *(const float4*)&outh[((size_t)(m0 + row) << 7) + (kh << 6) + (un << 2)];
      *(float4*)&Bs[(row << 6) + sw] =
          *(const float4*)&dW[((size_t)(n0 + row) << 7) + (kh << 6) + (un << 2)];
    }
    __syncthreads();
#pragma unroll 4
    for (int k4 = 0; k4 < 16; ++k4) {
      float4 a[4], b[4];
#pragma unroll
      for (int ii = 0; ii < 4; ++ii) {
        const int row = (ty << 2) + ii;
        a[ii] = *(const float4*)&As[(row << 6) + (((k4 ^ row) & 15) << 2)];
      }
#pragma unroll
      for (int jj = 0; jj < 4; ++jj) {
        const int row = (tx << 2) + jj;
        b[jj] = *(const float4*)&Bs[(row << 6) + (((k4 ^ row) & 15) << 2)];
      }
#pragma unroll
      for (int ii = 0; ii < 4; ++ii)
#pragma unroll
        for (int jj = 0; jj < 4; ++jj)
          acc[ii][jj] = fmaf(a[ii].x, b[jj].x, fmaf(a[ii].y, b[jj].y,
                        fmaf(a[ii].z, b[jj].z, fmaf(a[ii].w, b[jj].w, acc[ii][jj]))));
    }
    __syncthreads();
  }
#pragma unroll
  for (int ii = 0; ii < 4; ++ii) {
    const int m = m0 + (ty << 2) + ii;
    const int v0 = n0 + (tx << 2);
    float4 o;
    o.x = acc[ii][0] + dbv[v0];
    o.y = acc[ii][1] + dbv[v0 + 1];
    o.z = acc[ii][2] + dbv[v0 + 2];
    o.w = acc[ii][3] + dbv[v0 + 3];
    *(float4*)&dout[((size_t)m << 13) + v0] = o;
  }
}

extern "C" void kernel_launch(void* const* d_in, const int* in_sizes, int n_in,
                              void* d_out, int out_size, void* d_ws, size_t ws_size,
                              hipStream_t stream) {
  (void)in_sizes; (void)n_in; (void)out_size; (void)ws_size;
  const int*   x_seq = (const int*)d_in[0];
  const float* enc = (const float*)d_in[1];
  const float* vq  = (const float*)d_in[2];
  const float* nrg = (const float*)d_in[3];
  const float* nrb = (const float*)d_in[4];
  const float* nig = (const float*)d_in[5];
  const float* nib = (const float*)d_in[6];
  const float* qWr = (const float*)d_in[7];
  const float* qbr = (const float*)d_in[8];
  const float* qWi = (const float*)d_in[9];
  const float* qbi = (const float*)d_in[10];
  const float* gtw = (const float*)d_in[11];
  const float* gtb = (const float*)d_in[12];
  const float* aW  = (const float*)d_in[13];
  const float* ab  = (const float*)d_in[14];
  const float* dW  = (const float*)d_in[15];
  const float* db  = (const float*)d_in[16];
  const float* hb  = (const float*)d_in[17];
  const float* ig  = (const float*)d_in[18];
  char* ws = (char*)d_ws;
  float* out = (float*)d_out;
  hipLaunchKernelGGL(sacrsn_init, dim3(1), dim3(256), 0, stream, ws);
  hipLaunchKernelGGL(sacrsn_main, dim3(NBLK), dim3(NTHR), 0, stream,
                     x_seq, enc, vq, nrg, nrb, nig, nib, qWr, qbr, qWi, qbi,
                     gtw, gtb, aW, ab, hb, ig, out, ws);
  hipLaunchKernelGGL(sacrsn_dec, dim3(8192), dim3(256), 0, stream, dW, db, out, ws);
}

// Round 4
// 916.892 us; speedup vs baseline: 3.8038x; 1.0620x over previous
//
#include <hip/hip_runtime.h>
#include <math.h>

#define BB 128
#define TT 32
#define SS 32
#define VV 8192
#define MAXREC 8
#define NBLK 256
#define NTHR 256

// workspace byte offsets
#define OFF_ZBUF  0u          // 128*128 f32 = 65536 (z rows, linear)
#define OFF_FIN   65536u      // 2*128 u64 = 2048 (double-buffered argmin)
#define OFF_CTR   67584u      // 512 u32 = 2048 (barrier control block)
#define OFF_OUTH  69632u      // 4096*128 f32 = 2097152
#define OFF_RST   2166784u    // 128*4 f32

// ctr dword indices (64B padding between hot words)
#define C_AGRP(g)  ((g) * 16)          // g<4, owner arrival groups (cumulative)
#define C_AMID     64
#define C_BGRP(g)  (80 + (g) * 16)     // g<8, all-block arrival groups
#define C_BMID     208
#define C_AGENC(g) (224 + (g) * 16)    // 8 release words (A)
#define C_BGENC(g) (352 + (g) * 16)    // 8 release words (B)

#define SENT 0x7FFFFFFFu
#define LOGN 33554432u        // 128*32*8192
#define TWO_PI_F 6.283185307179586f

typedef float f32x4 __attribute__((ext_vector_type(4)));

__device__ __forceinline__ float wredsum(float v) {
#pragma unroll
  for (int m = 32; m > 0; m >>= 1) v += __shfl_xor(v, m);
  return v;
}

// monotone float->u32, pack with idx: u64-min == (min dist, then min idx) == jnp.argmin tie-break
__device__ __forceinline__ unsigned long long packkey(float d, unsigned c) {
  unsigned u = __float_as_uint(d);
  u = (u & 0x80000000u) ? ~u : (u | 0x80000000u);
  return ((unsigned long long)u << 32) | c;
}
__device__ __forceinline__ float unpackd2(unsigned long long key) {
  unsigned hi = (unsigned)(key >> 32);
  unsigned orig = (hi & 0x80000000u) ? (hi & 0x7fffffffu) : ~hi;
  return __uint_as_float(orig);
}

// ---- coherent (cross-XCD, L2-bypass) accesses: no cache-maintenance walks ----
__device__ __forceinline__ unsigned ld_coh32(const unsigned* p) {
  unsigned v;
  asm volatile("global_load_dword %0, %1, off sc0 sc1\n\ts_waitcnt vmcnt(0)"
               : "=&v"(v) : "v"(p) : "memory");
  return v;
}
__device__ __forceinline__ unsigned long long ld_coh64(const unsigned long long* p) {
  unsigned long long v;
  asm volatile("global_load_dwordx2 %0, %1, off sc0 sc1\n\ts_waitcnt vmcnt(0)"
               : "=&v"(v) : "v"(p) : "memory");
  return v;
}
__device__ __forceinline__ void st_coh_f32(float* p, float v) {
  asm volatile("global_store_dword %0, %1, off sc0 sc1" :: "v"(p), "v"(v) : "memory");
}
__device__ __forceinline__ void st_coh32(unsigned* p, unsigned v) {
  asm volatile("global_store_dword %0, %1, off sc0 sc1" :: "v"(p), "v"(v) : "memory");
}
__device__ __forceinline__ void st_coh64(unsigned long long* p, unsigned long long v) {
  asm volatile("global_store_dwordx2 %0, %1, off sc0 sc1" :: "v"(p), "v"(v) : "memory");
}

__device__ __forceinline__ unsigned rmw_inc(unsigned* p) {
  return __hip_atomic_fetch_add(p, 1u, __ATOMIC_RELAXED, __HIP_MEMORY_SCOPE_AGENT);
}

__device__ __forceinline__ unsigned poll_ge(const unsigned* p, unsigned tgt) {
  unsigned v = ld_coh32(p);
  while ((int)(v - tgt) < 0) {
    __builtin_amdgcn_s_sleep(4);
    v = ld_coh32(p);
  }
  return v;
}

// issue 8 coherent 16B loads, NO wait
__device__ __forceinline__ void ld8_issue(const float* base,
    unsigned o0, unsigned o1, unsigned o2, unsigned o3,
    unsigned o4, unsigned o5, unsigned o6, unsigned o7,
    f32x4& a0, f32x4& a1, f32x4& a2, f32x4& a3,
    f32x4& a4, f32x4& a5, f32x4& a6, f32x4& a7) {
  asm volatile(
      "global_load_dwordx4 %0, %8, %16 sc0 sc1\n\t"
      "global_load_dwordx4 %1, %9, %16 sc0 sc1\n\t"
      "global_load_dwordx4 %2, %10, %16 sc0 sc1\n\t"
      "global_load_dwordx4 %3, %11, %16 sc0 sc1\n\t"
      "global_load_dwordx4 %4, %12, %16 sc0 sc1\n\t"
      "global_load_dwordx4 %5, %13, %16 sc0 sc1\n\t"
      "global_load_dwordx4 %6, %14, %16 sc0 sc1\n\t"
      "global_load_dwordx4 %7, %15, %16 sc0 sc1"
      : "=&v"(a0), "=&v"(a1), "=&v"(a2), "=&v"(a3),
        "=&v"(a4), "=&v"(a5), "=&v"(a6), "=&v"(a7)
      : "v"(o0), "v"(o1), "v"(o2), "v"(o3),
        "v"(o4), "v"(o5), "v"(o6), "v"(o7),
        "s"(base)
      : "memory");
}
// issue 8 more + wait for ALL 16 (first 8 tied through as "+v")
__device__ __forceinline__ void ld8_wait(const float* base,
    unsigned o0, unsigned o1, unsigned o2, unsigned o3,
    unsigned o4, unsigned o5, unsigned o6, unsigned o7,
    f32x4& a0, f32x4& a1, f32x4& a2, f32x4& a3,
    f32x4& a4, f32x4& a5, f32x4& a6, f32x4& a7,
    f32x4& t0, f32x4& t1, f32x4& t2, f32x4& t3,
    f32x4& t4, f32x4& t5, f32x4& t6, f32x4& t7) {
  asm volatile(
      "global_load_dwordx4 %0, %16, %24 sc0 sc1\n\t"
      "global_load_dwordx4 %1, %17, %24 sc0 sc1\n\t"
      "global_load_dwordx4 %2, %18, %24 sc0 sc1\n\t"
      "global_load_dwordx4 %3, %19, %24 sc0 sc1\n\t"
      "global_load_dwordx4 %4, %20, %24 sc0 sc1\n\t"
      "global_load_dwordx4 %5, %21, %24 sc0 sc1\n\t"
      "global_load_dwordx4 %6, %22, %24 sc0 sc1\n\t"
      "global_load_dwordx4 %7, %23, %24 sc0 sc1\n\t"
      "s_waitcnt vmcnt(0)"
      : "=&v"(a0), "=&v"(a1), "=&v"(a2), "=&v"(a3),
        "=&v"(a4), "=&v"(a5), "=&v"(a6), "=&v"(a7),
        "+v"(t0), "+v"(t1), "+v"(t2), "+v"(t3),
        "+v"(t4), "+v"(t5), "+v"(t6), "+v"(t7)
      : "v"(o0), "v"(o1), "v"(o2), "v"(o3),
        "v"(o4), "v"(o5), "v"(o6), "v"(o7),
        "s"(base)
      : "memory");
}

__global__ __launch_bounds__(512) void sacrsn_init(char* __restrict__ ws) {
  unsigned long long* fin = (unsigned long long*)(ws + OFF_FIN);
  unsigned* ctr = (unsigned*)(ws + OFF_CTR);
  const int tid = threadIdx.x;
  if (tid < 256) fin[tid] = ~0ull;
  ctr[tid] = 0u;
}

__global__ __launch_bounds__(NTHR) void sacrsn_main(
    const int* __restrict__ x_seq, const float* __restrict__ enc,
    const float* __restrict__ vqe,
    const float* __restrict__ nrg, const float* __restrict__ nrb,
    const float* __restrict__ nig, const float* __restrict__ nib,
    const float* __restrict__ qWr, const float* __restrict__ qbr,
    const float* __restrict__ qWi, const float* __restrict__ qbi,
    const float* __restrict__ gtw, const float* __restrict__ gtb,
    const float* __restrict__ aW, const float* __restrict__ ab,
    const float* __restrict__ hbp, const float* __restrict__ igp,
    float* __restrict__ dout, char* __restrict__ ws)
{
  float* zbuf  = (float*)(ws + OFF_ZBUF);
  unsigned long long* fin = (unsigned long long*)(ws + OFF_FIN);
  unsigned* ctr = (unsigned*)(ws + OFF_CTR);
  float* outh  = (float*)(ws + OFF_OUTH);
  float* rst   = (float*)(ws + OFF_RST);

  const int tid = threadIdx.x;
  const int wv = tid >> 6, ln = tid & 63;
  const int blk = blockIdx.x;
  const bool owner = (blk < 128);

  // ---- LDS ----
  __shared__ float els[32 * 128];      // this block's 32 codes, unit-swizzled
  __shared__ float zloc[128 * 128];    // all rows' z, unit-swizzled
  __shared__ float memLr[32 * 65];
  __shared__ float memLi[32 * 65];
  __shared__ unsigned long long vtmp[128][8];
  __shared__ float gwrowL[128], pangL[64], zfmL[128], zqL[128];
  __shared__ float qkL[6][64], simL[32], attnL[32], mrL[64], miL[64];
  __shared__ unsigned idxL[128];
  __shared__ float arbWL[3 * 128];
  __shared__ float esqL[32];
  __shared__ float z2locL[128];
  __shared__ float scalL[8], arbL[4], entpL[2], vqpL[2], wsumL[2];
  __shared__ float accL[4], totL[4];
  __shared__ unsigned long long actM[2], actN[2];
  __shared__ unsigned stopF;

  const float alpha = 1.0f / (1.0f + expf(-igp[0]));
  const float onema = 1.0f - alpha;
  const float hbias = log1pf(expf(hbp[0]));
  const float gtb0 = gtb[0];

  float lnG = 0.0f, lnB = 0.0f, gtwv = 0.0f;
  if (owner) {
    if (tid < 64) { lnG = nrg[tid]; lnB = nrb[tid]; }
    else if (tid < 128) { lnG = nig[tid - 64]; lnB = nib[tid - 64]; }
    if (tid < 128) gtwv = gtw[tid];
  }

  // ---- one-time LDS init ----
  if (owner) {
    for (int i = tid; i < 32 * 65; i += 256) { memLr[i] = 0.0f; memLi[i] = 0.0f; }
    if (tid < 128) gwrowL[tid] = 0.0f;
    if (tid < 4) { totL[tid] = 0.0f; accL[tid] = 0.0f; }
    for (int i = tid; i < 384; i += 256) arbWL[i] = aW[i];
  }
#pragma unroll
  for (int j = 0; j < 4; ++j) {
    int f4 = tid + j * 256;
    int c = f4 >> 5, k4 = f4 & 31;
    float4 v = *(const float4*)&vqe[((size_t)(blk * 32 + c) << 7) + (k4 << 2)];
    *(float4*)&els[(c << 7) + ((k4 ^ c) << 2)] = v;
  }
  __syncthreads();
  if (tid < 32) {
    float s = 0.0f;
#pragma unroll 8
    for (int k4 = 0; k4 < 32; ++k4) {
      float4 v = *(const float4*)&els[(tid << 7) + ((k4 ^ tid) << 2)];
      s = fmaf(v.x, v.x, fmaf(v.y, v.y, fmaf(v.z, v.z, fmaf(v.w, v.w, s))));
    }
    esqL[tid] = s;
  }
  __syncthreads();

  // ================= shared B phase (VQ servers + owners) =================
  auto bphase = [&](unsigned kk) {
    const unsigned pc = kk & 1u;
    if (owner && tid == 0) st_coh64(&fin[(pc ^ 1u) * 128 + blk], ~0ull);
    // stage all rows' z into LDS: 16 coherent 16B loads, single round trip
    {
      f32x4 va0, va1, va2, va3, va4, va5, va6, va7;
      f32x4 vb0, vb1, vb2, vb3, vb4, vb5, vb6, vb7;
      const unsigned tb = (unsigned)tid * 16u;
      ld8_issue(zbuf,
                tb, tb + 4096u, tb + 8192u, tb + 12288u,
                tb + 16384u, tb + 20480u, tb + 24576u, tb + 28672u,
                va0, va1, va2, va3, va4, va5, va6, va7);
      ld8_wait(zbuf,
               tb + 32768u, tb + 36864u, tb + 40960u, tb + 45056u,
               tb + 49152u, tb + 53248u, tb + 57344u, tb + 61440u,
               vb0, vb1, vb2, vb3, vb4, vb5, vb6, vb7,
               va0, va1, va2, va3, va4, va5, va6, va7);
      __builtin_amdgcn_sched_barrier(0);
      f32x4 va[16] = {va0, va1, va2, va3, va4, va5, va6, va7,
                      vb0, vb1, vb2, vb3, vb4, vb5, vb6, vb7};
#pragma unroll
      for (int u = 0; u < 16; ++u) {
        int f4 = u * 256 + tid;
        int row = f4 >> 5, k4 = f4 & 31;
        *(f32x4*)&zloc[(row << 7) + ((k4 ^ (row & 31)) << 2)] = va[u];
      }
    }
    __syncthreads();
    // per-row z^2 (local; argmin invariant to the per-row constant)
    if (tid < 128) {
      float s = 0.0f;
#pragma unroll 8
      for (int k4 = 0; k4 < 32; ++k4) {
        float4 q = *(const float4*)&zloc[(tid << 7) + ((k4 ^ (tid & 31)) << 2)];
        s = fmaf(q.x, q.x, fmaf(q.y, q.y, fmaf(q.z, q.z, fmaf(q.w, q.w, s))));
      }
      z2locL[tid] = s;
    }
    // VQ: 32 codes x 128 rows, 4x4 register tiles
    const int rt = ln & 7, ct = ln >> 3;
    int rowA[4];
#pragma unroll
    for (int rr = 0; rr < 4; ++rr) rowA[rr] = (wv << 5) + rt + rr * 8;
    float acc[4][4];
#pragma unroll
    for (int rr = 0; rr < 4; ++rr)
#pragma unroll
      for (int cc = 0; cc < 4; ++cc) acc[rr][cc] = 0.0f;
#pragma unroll 2
    for (int k4 = 0; k4 < 32; ++k4) {
      float4 zv[4], ev[4];
#pragma unroll
      for (int rr = 0; rr < 4; ++rr) {
        int rs = rt + rr * 8;
        zv[rr] = *(const float4*)&zloc[(rowA[rr] << 7) + ((k4 ^ rs) << 2)];
      }
#pragma unroll
      for (int cc = 0; cc < 4; ++cc) {
        int cl = ct + cc * 8;
        ev[cc] = *(const float4*)&els[(cl << 7) + ((k4 ^ cl) << 2)];
      }
#pragma unroll
      for (int rr = 0; rr < 4; ++rr)
#pragma unroll
        for (int cc = 0; cc < 4; ++cc)
          acc[rr][cc] = fmaf(zv[rr].x, ev[cc].x, fmaf(zv[rr].y, ev[cc].y,
                        fmaf(zv[rr].z, ev[cc].z, fmaf(zv[rr].w, ev[cc].w, acc[rr][cc]))));
    }
    __syncthreads();  // z2locL ready
    {
      float z2r[4];
#pragma unroll
      for (int rr = 0; rr < 4; ++rr) z2r[rr] = z2locL[rowA[rr]];
#pragma unroll
      for (int rr = 0; rr < 4; ++rr) {
        unsigned long long key = ~0ull;
#pragma unroll
        for (int cc = 0; cc < 4; ++cc) {
          int cl = ct + cc * 8;
          float d2 = (z2r[rr] - 2.0f * acc[rr][cc]) + esqL[cl];
          unsigned long long pk = packkey(d2, (unsigned)(blk * 32 + cl));
          if (pk < key) key = pk;
        }
        vtmp[rowA[rr]][ct] = key;
      }
    }
    __syncthreads();
    if (tid < 128) {
      unsigned long long kmin = vtmp[tid][0];
#pragma unroll
      for (int w = 1; w < 8; ++w) { unsigned long long o = vtmp[tid][w]; if (o < kmin) kmin = o; }
      unsigned long long cur = ld_coh64(&fin[pc * 128 + tid]);
      if (kmin < cur) atomicMin(&fin[pc * 128 + tid], kmin);
    }
    __syncthreads();  // drain atomics (per-wave vmcnt at barrier)
    if (tid == 0) {   // B arrival: 8x32 cumulative -> mid -> 8 release words
      unsigned a = rmw_inc(&ctr[C_BGRP(blk >> 5)]);
      if ((a & 31u) == 31u) {
        unsigned b = rmw_inc(&ctr[C_BMID]);
        if ((b & 7u) == 7u) {
#pragma unroll
          for (int g = 0; g < 8; ++g) st_coh32(&ctr[C_BGENC(g)], kk + 1u);
        }
      }
    }
  };

  // ================= non-owners: stateless VQ servers =================
  if (!owner) {
    unsigned k = 0;
    while (true) {
      if (tid == 0) {
        unsigned v = poll_ge(&ctr[C_AGENC(blk >> 5)], k + 1u);
        stopF = (v >= 0x7F000000u) ? 1u : 0u;
      }
      __syncthreads();
      if (stopF) break;
      bphase(k);
      k++;
    }
    return;
  }

  // ================= owners: recurrence =================
  unsigned k = 0;
  for (int t = 0; t < TT; ++t) {
    for (int it = 0; it < MAXREC; ++it) {
      // ---------- A: merge (it0) + LN own row -> zbuf ----------
      if (it == 0 && tid < 2) actM[tid] = ~0ull;
      float val = 0.0f;
      if (it == 0) {
        float pr = 0.0f, gr = 0.0f;
        if (tid < 128) {
          pr = gwrowL[tid];
          int tok = x_seq[blk * TT + t];
          gr = fmaf(alpha, pr, onema * enc[((size_t)tok << 7) + tid]);
        }
        if (t > 0 && tid < 128) {
          outh[((size_t)blk * TT + (t - 1)) * 128 + tid] = pr;
          float part = wredsum(pr * gtwv);
          if (ln == 0) wsumL[wv] = part;
        }
        if (tid < 4) { if (t > 0) totL[tid] += accL[tid]; accL[tid] = 0.0f; }
        if (tid >= 64 && tid < 128) zqL[tid - 64] = gr;  // gi exchange
        __syncthreads();
        if (t > 0 && tid < 128) {
          float wg = 1.0f / (1.0f + expf(-(wsumL[0] + wsumL[1] + gtb0)));
          int slot = 32 - t;
          float* m = (tid < 64) ? &memLr[slot * 65 + tid] : &memLi[slot * 65 + (tid - 64)];
          *m = fmaf(wg, pr, (1.0f - wg) * (*m));
        }
        if (tid < 64) pangL[tid] = atan2f(zqL[tid], gr);
        if (tid < 128) gwrowL[tid] = gr;
        val = gr;
      } else {
        val = (tid < 128) ? gwrowL[tid] : 0.0f;
      }
      if (tid < 128) {
        float mu = wredsum(val) * 0.015625f;
        float xc = val - mu;
        float vr = wredsum(xc * xc) * 0.015625f;
        float z = xc * (1.0f / sqrtf(vr + 1e-5f)) * lnG + lnB;
        zfmL[tid] = z;
        st_coh_f32(&zbuf[(blk << 7) + tid], z);
      }
      __syncthreads();  // drains the z stores (per-wave vmcnt)
      if (tid == 0) {   // A arrival: 4x32 cumulative -> mid -> 8 release words
        unsigned a = rmw_inc(&ctr[C_AGRP(blk >> 5)]);
        if ((a & 31u) == 31u) {
          unsigned b = rmw_inc(&ctr[C_AMID]);
          if ((b & 3u) == 3u) {
#pragma unroll
            for (int g = 0; g < 8; ++g) st_coh32(&ctr[C_AGENC(g)], k + 1u);
          }
        }
        poll_ge(&ctr[C_AGENC(blk >> 5)], k + 1u);
      }
      __syncthreads();
      // ---------- B ----------
      bphase(k);
      if (tid == 0) poll_ge(&ctr[C_BGENC(blk >> 4)], k + 1u);
      __syncthreads();
      // ---------- consensus: idx + halt mask from fin keys ----------
      const unsigned pc = k & 1u;
      const bool aoldb = ((actM[blk >> 6] >> (blk & 63)) & 1ull) != 0ull;
      if (tid < 128) {
        unsigned long long key = ld_coh64(&fin[pc * 128 + tid]);
        idxL[tid] = (unsigned)key;
        float d2 = unpackd2(key);
        bool act_b = ((actM[tid >> 6] >> (tid & 63)) & 1ull) != 0ull;
        bool stop = (1.25f * 0.0078125f * d2) < hbias;  // pure fn of key -> identical everywhere
        unsigned long long ball = __ballot(act_b && !stop);
        if ((tid & 63) == 0) actN[tid >> 6] = ball;
      }
      __syncthreads();
      const bool anyAct = (actN[0] | actN[1]) != 0ull;
      if (tid < 2) actM[tid] = actN[tid];
      // ---------- C: row update ----------
      {
        const unsigned ii = idxL[blk];
        const bool mf = aoldb;
        const float aold = mf ? 1.0f : 0.0f;
        // s1: entropy (waves 0-1), vq_loss + z_q fetch (waves 2-3)
        if (tid < 128) {
          unsigned my = idxL[tid];
          int c = 0;
          for (int j = 0; j < 128; ++j) c += (idxL[j] == my) ? 1 : 0;
          float term = -0.0078125f * logf((float)c * 0.0078125f + 1e-10f);
          term = wredsum(term);
          if (ln == 0) entpL[wv] = term;
        } else {
          int d = tid - 128;
          float zq = vqe[((size_t)ii << 7) + d];
          zqL[d] = zq;
          float df = zq - zfmL[d];
          float s = wredsum(df * df);
          if (ln == 0) vqpL[wv - 2] = s;
        }
        __syncthreads();
        // s2: clin q,k,v (0..191) | sim (192..223) | arb (224..226)
        if (tid < 192) {
          const int h = tid >> 6, j = tid & 63;
          const float* wr = qWr + h * 4096 + j * 64;
          const float* wi = qWi + h * 4096 + j * 64;
          float da = 0.0f, db_ = 0.0f, dc = 0.0f, de = 0.0f;
#pragma unroll 4
          for (int d4 = 0; d4 < 64; d4 += 4) {
            float4 wrv = *(const float4*)&wr[d4];
            float4 wiv = *(const float4*)&wi[d4];
            float4 crv = *(const float4*)&zfmL[d4];
            float4 civ = *(const float4*)&zfmL[64 + d4];
            da = fmaf(crv.x, wrv.x, fmaf(crv.y, wrv.y, fmaf(crv.z, wrv.z, fmaf(crv.w, wrv.w, da))));
            db_ = fmaf(civ.x, wiv.x, fmaf(civ.y, wiv.y, fmaf(civ.z, wiv.z, fmaf(civ.w, wiv.w, db_))));
            dc = fmaf(civ.x, wrv.x, fmaf(civ.y, wrv.y, fmaf(civ.z, wrv.z, fmaf(civ.w, wrv.w, dc))));
            de = fmaf(crv.x, wiv.x, fmaf(crv.y, wiv.y, fmaf(crv.z, wiv.z, fmaf(crv.w, wiv.w, de))));
          }
          float brv = qbr[h * 64 + j], biv = qbi[h * 64 + j];
          qkL[2 * h][j] = da + brv - db_ - biv;
          qkL[2 * h + 1][j] = dc + brv + de + biv;
        } else if (tid < 224) {
          const int s = tid - 192;
          float a2 = 0.0f;
          for (int d = 0; d < 64; ++d)
            a2 = fmaf(memLr[s * 65 + d], zfmL[d], fmaf(memLi[s * 65 + d], zfmL[64 + d], a2));
          simL[s] = a2;
        } else if (tid < 227) {
          const int h = tid - 224;
          float a2 = ab[h];
          for (int k2 = 0; k2 < 128; ++k2) a2 = fmaf(zfmL[k2], arbWL[h * 128 + k2], a2);
          arbL[h] = a2;
        }
        __syncthreads();
        // s3: gate | attn softmax | arb softmax | scalar combines
        if (tid < 64) {
          float p = fmaf(qkL[0][tid], qkL[2][tid], qkL[1][tid] * qkL[3][tid]);
          p = wredsum(p);
          if (tid == 0) scalL[0] = 1.0f / (1.0f + expf(-p));
        } else if (tid < 96) {
          const int s = tid - 64;
          float v = simL[s];
          float m = v;
#pragma unroll
          for (int msk = 16; msk > 0; msk >>= 1) m = fmaxf(m, __shfl_xor(m, msk));
          float e = expf(v - m);
          float ss = e;
#pragma unroll
          for (int msk = 16; msk > 0; msk >>= 1) ss += __shfl_xor(ss, msk);
          attnL[s] = e / ss;
        } else if (tid == 96) {
          float a0 = arbL[0], a1 = arbL[1], a2 = arbL[2];
          float m = fmaxf(a0, fmaxf(a1, a2));
          float e0 = expf(a0 - m), e1 = expf(a1 - m), e2 = expf(a2 - m);
          float s = e0 + e1 + e2;
          scalL[3] = e0 / s; scalL[4] = e1 / s; scalL[5] = e2 / s;
        } else if (tid == 97) {
          scalL[2] = entpL[0] + entpL[1];
          scalL[1] = 1.25f * (vqpL[0] + vqpL[1]) * 0.0078125f;
        }
        __syncthreads();
        // s4: attention readout m_r / m_i
        if (tid < 128) {
          const int d = ln;
          const float* ml = (wv == 0) ? memLr : memLi;
          float a2 = 0.0f;
#pragma unroll 4
          for (int s2 = 0; s2 < 32; ++s2) a2 = fmaf(attnL[s2], ml[s2 * 65 + d], a2);
          if (wv == 0) mrL[d] = a2; else miL[d] = a2;
        }
        __syncthreads();
        // s5: candidate, phase diff, stats
        if (tid < 64) {
          const int d = tid;
          float gate = scalL[0], g0 = scalL[3], g1 = scalL[4], g2 = scalL[5];
          float cr = zfmL[d], ci = zfmL[64 + d];
          float ur = fmaf(g0, qkL[4][d] * gate, fmaf(g1, mrL[d], g2 * zqL[d]));
          float ui = fmaf(g0, qkL[5][d] * gate, fmaf(g1, miL[d], g2 * zqL[64 + d]));
          float cdr = fmaf(0.4f, ur, 0.6f * cr);
          float cdi = fmaf(0.4f, ui, 0.6f * ci);
          float ang = atan2f(cdi, cdr);
          float df = fabsf(ang - pangL[d]);
          df = fminf(df, TWO_PI_F - df);
          pangL[d] = ang;
          float dmean = wredsum(df) * 0.015625f;
          if (mf) { gwrowL[d] = cdr; gwrowL[64 + d] = cdi; }
          if (d == 0) {
            accL[3] += aold * dmean;
            accL[2] += aold * 0.01f;
            if (mf) {
              accL[0] = scalL[1];
              accL[1] = scalL[2];
              dout[(size_t)LOGN + 4 + (size_t)blk * TT + t] = (float)ii;
            }
          }
        }
        __syncthreads();
      }
      k++;
      if (!anyAct) break;
    } // it
  } // t

  // epilogue: final gw out + stats flush + sentinel release for VQ servers
  if (tid < 128) outh[((size_t)blk * TT + (TT - 1)) * 128 + tid] = gwrowL[tid];
  if (tid < 4) rst[blk * 4 + tid] = totL[tid] + accL[tid];
  __syncthreads();
  if (tid == 0) {
    unsigned a = rmw_inc(&ctr[C_AGRP(blk >> 5)]);
    if ((a & 31u) == 31u) {
      unsigned b = rmw_inc(&ctr[C_AMID]);
      if ((b & 3u) == 3u) {
#pragma unroll
        for (int g = 0; g < 8; ++g) st_coh32(&ctr[C_AGENC(g)], SENT);
      }
    }
  }
}

__global__ __launch_bounds__(256) void sacrsn_dec(
    const float* __restrict__ dW, const float* __restrict__ dbv,
    float* __restrict__ dout, const char* __restrict__ ws)
{
  const float* outh = (const float*)(ws + OFF_OUTH);
  const float* rst = (const float*)(ws + OFF_RST);
  __shared__ float As[4096];
  __shared__ float Bs[4096];
  const int tid = threadIdx.x;
  const int bx = blockIdx.x & 127;
  const int by = blockIdx.x >> 7;
  const int n0 = bx << 6, m0 = by << 6;
  if (blockIdx.x == 0 && tid < 4) {
    float s = 0.0f;
    for (int r = 0; r < 128; ++r) s += rst[r * 4 + tid];
    dout[(size_t)LOGN + tid] = s * (1.0f / 4096.0f);
  }
  const int ty = tid >> 4, tx = tid & 15;
  float acc[4][4];
#pragma unroll
  for (int i = 0; i < 4; ++i)
#pragma unroll
    for (int j = 0; j < 4; ++j) acc[i][j] = 0.0f;
  for (int kh = 0; kh < 2; ++kh) {
    for (int u = tid; u < 1024; u += 256) {
      const int row = u >> 4, un = u & 15;
      const int sw = ((un ^ row) & 15) << 2;
      *(float4*)&As[(row << 6) + sw] =
          *(const float4*)&outh[((size_t)(m0 + row) << 7) + (kh << 6) + (un << 2)];
      *(float4*)&Bs[(row << 6) + sw] =
          *(const float4*)&dW[((size_t)(n0 + row) << 7) + (kh << 6) + (un << 2)];
    }
    __syncthreads();
#pragma unroll 4
    for (int k4 = 0; k4 < 16; ++k4) {
      float4 a[4], b[4];
#pragma unroll
      for (int ii = 0; ii < 4; ++ii) {
        const int row = (ty << 2) + ii;
        a[ii] = *(const float4*)&As[(row << 6) + (((k4 ^ row) & 15) << 2)];
      }
#pragma unroll
      for (int jj = 0; jj < 4; ++jj) {
        const int row = (tx << 2) + jj;
        b[jj] = *(const float4*)&Bs[(row << 6) + (((k4 ^ row) & 15) << 2)];
      }
#pragma unroll
      for (int ii = 0; ii < 4; ++ii)
#pragma unroll
        for (int jj = 0; jj < 4; ++jj)
          acc[ii][jj] = fmaf(a[ii].x, b[jj].x, fmaf(a[ii].y, b[jj].y,
                        fmaf(a[ii].z, b[jj].z, fmaf(a[ii].w, b[jj].w, acc[ii][jj]))));
    }
    __syncthreads();
  }
#pragma unroll
  for (int ii = 0; ii < 4; ++ii) {
    const int m = m0 + (ty << 2) + ii;
    const int v0 = n0 + (tx << 2);
    float4 o;
    o.x = acc[ii][0] + dbv[v0];
    o.y = acc[ii][1] + dbv[v0 + 1];
    o.z = acc[ii][2] + dbv[v0 + 2];
    o.w = acc[ii][3] + dbv[v0 + 3];
    *(float4*)&dout[((size_t)m << 13) + v0] = o;
  }
}

extern "C" void kernel_launch(void* const* d_in, const int* in_sizes, int n_in,
                              void* d_out, int out_size, void* d_ws, size_t ws_size,
                              hipStream_t stream) {
  (void)in_sizes; (void)n_in; (void)out_size; (void)ws_size;
  const int*   x_seq = (const int*)d_in[0];
  const float* enc = (const float*)d_in[1];
  const float* vq  = (const float*)d_in[2];
  const float* nrg = (const float*)d_in[3];
  const float* nrb = (const float*)d_in[4];
  const float* nig = (const float*)d_in[5];
  const float* nib = (const float*)d_in[6];
  const float* qWr = (const float*)d_in[7];
  const float* qbr = (const float*)d_in[8];
  const float* qWi = (const float*)d_in[9];
  const float* qbi = (const float*)d_in[10];
  const float* gtw = (const float*)d_in[11];
  const float* gtb = (const float*)d_in[12];
  const float* aW  = (const float*)d_in[13];
  const float* ab  = (const float*)d_in[14];
  const float* dW  = (const float*)d_in[15];
  const float* db  = (const float*)d_in[16];
  const float* hb  = (const float*)d_in[17];
  const float* ig  = (const float*)d_in[18];
  char* ws = (char*)d_ws;
  float* out = (float*)d_out;
  hipLaunchKernelGGL(sacrsn_init, dim3(1), dim3(512), 0, stream, ws);
  hipLaunchKernelGGL(sacrsn_main, dim3(NBLK), dim3(NTHR), 0, stream,
                     x_seq, enc, vq, nrg, nrb, nig, nib, qWr, qbr, qWi, qbi,
                     gtw, gtb, aW, ab, hb, ig, out, ws);
  hipLaunchKernelGGL(sacrsn_dec, dim3(8192), dim3(256), 0, stream, dW, db, out, ws);
}